// Round 4
// baseline (182.247 us; speedup 1.0000x reference)
//
#include <hip/hip_runtime.h>
#include <hip/hip_bf16.h>

#define NUMW 4096
#define IN_F 100
#define HID  30

typedef float float4n __attribute__((ext_vector_type(4)));

// ---------- stage 1: A = relu(oo@Wp+bp); P = A@W1; Qb = A@W2 + bc ----------
// All inputs are FLOAT32 (reference dtypes). 512 blocks x 256 threads, 8 rows/block.
__global__ __launch_bounds__(256) void stage1(
    const float* __restrict__ oo,
    const float* __restrict__ Wp,
    const float* __restrict__ bp,
    const float* __restrict__ Wc,
    const float* __restrict__ bc,
    float* __restrict__ Pbuf, float* __restrict__ Qbuf)
{
    __shared__ float Wp_s[IN_F * HID];   // 3000 f32 = 12 KB
    __shared__ float oo_s[8][IN_F];      // 3.2 KB
    __shared__ float A_s[8 * HID];       // 0.96 KB
    const int tid = threadIdx.x;
    const int i0  = blockIdx.x * 8;

    // Wp: 3000 f32
    for (int t = tid; t < IN_F * HID; t += 256) Wp_s[t] = Wp[t];

    // oo rows i0..i0+7: row = 100 f32 = 400 B = 25 float4 (16B-aligned)
    const float4* oo4 = (const float4*)oo;
    for (int t = tid; t < 8 * 25; t += 256) {
        int r = t / 25, c = t % 25;
        float4 v = oo4[(size_t)(i0 + r) * 25 + c];
        oo_s[r][4 * c]     = v.x;
        oo_s[r][4 * c + 1] = v.y;
        oo_s[r][4 * c + 2] = v.z;
        oo_s[r][4 * c + 3] = v.w;
    }
    __syncthreads();

    // phase 1: thread (r,h) -> A[i0+r][h]
    if (tid < 8 * HID) {
        int r = tid / HID, h = tid % HID;
        float a0 = bp[h], a1 = 0.f;
        #pragma unroll
        for (int k = 0; k < IN_F; k += 2) {
            a0 += oo_s[r][k]     * Wp_s[k * HID + h];
            a1 += oo_s[r][k + 1] * Wp_s[(k + 1) * HID + h];
        }
        float a = a0 + a1;
        A_s[r * HID + h] = a > 0.f ? a : 0.f;
    }
    __syncthreads();

    // phase 2: 32 threads -> P[i,c] and Qb[i,c] = Q[i,c] + bc[c]
    if (tid < 32) {
        int r = tid >> 2, q = tid & 3;
        int c = q & 1, isQ = q >> 1;
        float acc = isQ ? bc[c] : 0.f;
        int hoff = isQ * HID;
        #pragma unroll
        for (int hh = 0; hh < HID; ++hh)
            acc += A_s[r * HID + hh] * Wc[(hoff + hh) * 2 + c];
        int i = i0 + r;
        if (isQ) Qbuf[i * 2 + c] = acc;
        else     Pbuf[i * 2 + c] = acc;
    }
}

// ---------- stage 2: out[i,j,c] = relu(P[i,c] + Qb[j,c]), f32 output ----------
// grid (4, 1024), 256 threads. Thread: 4 j's (8 f32 = 32B) x 4 i rows.
__global__ __launch_bounds__(256) void stage2(
    const float* __restrict__ Pbuf, const float* __restrict__ Qbuf,
    float* __restrict__ out)
{
    const int tid = threadIdx.x;
    const int j0  = (blockIdx.x * 256 + tid) * 4;
    const int i0  = blockIdx.y * 4;

    const float4n* q4 = (const float4n*)(Qbuf + (size_t)j0 * 2);  // 32B aligned
    float4n qa = q4[0], qb = q4[1];

    #pragma unroll
    for (int r = 0; r < 4; ++r) {
        int i = i0 + r;
        float p0 = Pbuf[i * 2], p1 = Pbuf[i * 2 + 1];  // block-uniform -> scalar
        float4n o0, o1;
        o0.x = fmaxf(p0 + qa.x, 0.f); o0.y = fmaxf(p1 + qa.y, 0.f);
        o0.z = fmaxf(p0 + qa.z, 0.f); o0.w = fmaxf(p1 + qa.w, 0.f);
        o1.x = fmaxf(p0 + qb.x, 0.f); o1.y = fmaxf(p1 + qb.y, 0.f);
        o1.z = fmaxf(p0 + qb.z, 0.f); o1.w = fmaxf(p1 + qb.w, 0.f);
        float4n* dst = (float4n*)(out + ((size_t)i * NUMW + j0) * 2);
        __builtin_nontemporal_store(o0, dst);
        __builtin_nontemporal_store(o1, dst + 1);
    }
}

extern "C" void kernel_launch(void* const* d_in, const int* in_sizes, int n_in,
                              void* d_out, int out_size, void* d_ws, size_t ws_size,
                              hipStream_t stream) {
    const float* oo = (const float*)d_in[0];
    const float* Wp = (const float*)d_in[1];
    const float* bp = (const float*)d_in[2];
    const float* Wc = (const float*)d_in[3];
    const float* bc = (const float*)d_in[4];

    float* Pbuf = (float*)d_ws;              // 4096*2 f32
    float* Qbuf = Pbuf + NUMW * 2;           // 4096*2 f32 (bc folded in)

    stage1<<<dim3(NUMW / 8), 256, 0, stream>>>(oo, Wp, bp, Wc, bc, Pbuf, Qbuf);
    stage2<<<dim3(NUMW / 1024, NUMW / 4), 256, 0, stream>>>(
        Pbuf, Qbuf, (float*)d_out);
}

// Round 5
// 159.381 us; speedup vs baseline: 1.1435x; 1.1435x over previous
//
#include <hip/hip_runtime.h>
#include <hip/hip_bf16.h>

#define NUMW 4096
#define IN_F 100
#define HID  30

typedef float float4n __attribute__((ext_vector_type(4)));

// ---------- stage 1: A = relu(oo@Wp+bp); P = A@W1; Qb = A@W2 + bc ----------
// All inputs FLOAT32. 512 blocks x 256 threads, 8 rows/block.
__global__ __launch_bounds__(256) void stage1(
    const float* __restrict__ oo,
    const float* __restrict__ Wp,
    const float* __restrict__ bp,
    const float* __restrict__ Wc,
    const float* __restrict__ bc,
    float* __restrict__ Pbuf, float* __restrict__ Qbuf)
{
    __shared__ float Wp_s[IN_F * HID];   // 12 KB
    __shared__ float oo_s[8][IN_F];      // 3.2 KB
    __shared__ float A_s[8 * HID];       // 0.96 KB
    const int tid = threadIdx.x;
    const int i0  = blockIdx.x * 8;

    for (int t = tid; t < IN_F * HID; t += 256) Wp_s[t] = Wp[t];

    const float4* oo4 = (const float4*)oo;
    for (int t = tid; t < 8 * 25; t += 256) {
        int r = t / 25, c = t % 25;
        float4 v = oo4[(size_t)(i0 + r) * 25 + c];
        oo_s[r][4 * c]     = v.x;
        oo_s[r][4 * c + 1] = v.y;
        oo_s[r][4 * c + 2] = v.z;
        oo_s[r][4 * c + 3] = v.w;
    }
    __syncthreads();

    if (tid < 8 * HID) {
        int r = tid / HID, h = tid % HID;
        float a0 = bp[h], a1 = 0.f;
        #pragma unroll
        for (int k = 0; k < IN_F; k += 2) {
            a0 += oo_s[r][k]     * Wp_s[k * HID + h];
            a1 += oo_s[r][k + 1] * Wp_s[(k + 1) * HID + h];
        }
        float a = a0 + a1;
        A_s[r * HID + h] = a > 0.f ? a : 0.f;
    }
    __syncthreads();

    if (tid < 32) {
        int r = tid >> 2, q = tid & 3;
        int c = q & 1, isQ = q >> 1;
        float acc = isQ ? bc[c] : 0.f;
        int hoff = isQ * HID;
        #pragma unroll
        for (int hh = 0; hh < HID; ++hh)
            acc += A_s[r * HID + hh] * Wc[(hoff + hh) * 2 + c];
        int i = i0 + r;
        if (isQ) Qbuf[i * 2 + c] = acc;
        else     Pbuf[i * 2 + c] = acc;
    }
}

// ---------- stage 2: out[i,j,c] = relu(P[i,c] + Qb[j,c]), f32 output ----------
// grid (8, 256) x 256 threads. Thread: 2 j's (one float4 = 16B, lane-consecutive
// -> each store instruction covers 1 KB fully contiguous) x 16 i rows.
__global__ __launch_bounds__(256) void stage2(
    const float* __restrict__ Pbuf, const float* __restrict__ Qbuf,
    float* __restrict__ out)
{
    const int tid = threadIdx.x;
    const int j0  = blockIdx.x * 512 + tid * 2;   // 2 j's per thread
    const int i0  = blockIdx.y * 16;

    float4n q = *(const float4n*)(Qbuf + (size_t)j0 * 2);  // Qb[j0],Qb[j0+1] (16B)

    #pragma unroll
    for (int r = 0; r < 16; ++r) {
        int i = i0 + r;
        float p0 = Pbuf[i * 2], p1 = Pbuf[i * 2 + 1];  // block-uniform -> scalar
        float4n o;
        o.x = fmaxf(p0 + q.x, 0.f);
        o.y = fmaxf(p1 + q.y, 0.f);
        o.z = fmaxf(p0 + q.z, 0.f);
        o.w = fmaxf(p1 + q.w, 0.f);
        __builtin_nontemporal_store(o, (float4n*)(out + ((size_t)i * NUMW + j0) * 2));
    }
}

extern "C" void kernel_launch(void* const* d_in, const int* in_sizes, int n_in,
                              void* d_out, int out_size, void* d_ws, size_t ws_size,
                              hipStream_t stream) {
    const float* oo = (const float*)d_in[0];
    const float* Wp = (const float*)d_in[1];
    const float* bp = (const float*)d_in[2];
    const float* Wc = (const float*)d_in[3];
    const float* bc = (const float*)d_in[4];

    float* Pbuf = (float*)d_ws;              // 4096*2 f32
    float* Qbuf = Pbuf + NUMW * 2;           // 4096*2 f32 (bc folded in)

    stage1<<<dim3(NUMW / 8), 256, 0, stream>>>(oo, Wp, bp, Wc, bc, Pbuf, Qbuf);
    stage2<<<dim3(8, 256), 256, 0, stream>>>(Pbuf, Qbuf, (float*)d_out);
}

// Round 6
// 151.918 us; speedup vs baseline: 1.1996x; 1.0491x over previous
//
#include <hip/hip_runtime.h>
#include <hip/hip_bf16.h>

#define NUMW 4096
#define IN_F 100
#define HID  30

typedef float float4n __attribute__((ext_vector_type(4)));

// ---------- stage 1: A = relu(oo@Wp+bp); P = A@W1; Qb = A@W2 + bc ----------
// All inputs FLOAT32. 512 blocks x 256 threads, 8 rows/block.
__global__ __launch_bounds__(256) void stage1(
    const float* __restrict__ oo,
    const float* __restrict__ Wp,
    const float* __restrict__ bp,
    const float* __restrict__ Wc,
    const float* __restrict__ bc,
    float* __restrict__ Pbuf, float* __restrict__ Qbuf)
{
    __shared__ float Wp_s[IN_F * HID];   // 12 KB
    __shared__ float oo_s[8][IN_F];      // 3.2 KB
    __shared__ float A_s[8 * HID];       // 0.96 KB
    const int tid = threadIdx.x;
    const int i0  = blockIdx.x * 8;

    for (int t = tid; t < IN_F * HID; t += 256) Wp_s[t] = Wp[t];

    const float4* oo4 = (const float4*)oo;
    for (int t = tid; t < 8 * 25; t += 256) {
        int r = t / 25, c = t % 25;
        float4 v = oo4[(size_t)(i0 + r) * 25 + c];
        oo_s[r][4 * c]     = v.x;
        oo_s[r][4 * c + 1] = v.y;
        oo_s[r][4 * c + 2] = v.z;
        oo_s[r][4 * c + 3] = v.w;
    }
    __syncthreads();

    if (tid < 8 * HID) {
        int r = tid / HID, h = tid % HID;
        float a0 = bp[h], a1 = 0.f;
        #pragma unroll
        for (int k = 0; k < IN_F; k += 2) {
            a0 += oo_s[r][k]     * Wp_s[k * HID + h];
            a1 += oo_s[r][k + 1] * Wp_s[(k + 1) * HID + h];
        }
        float a = a0 + a1;
        A_s[r * HID + h] = a > 0.f ? a : 0.f;
    }
    __syncthreads();

    if (tid < 32) {
        int r = tid >> 2, q = tid & 3;
        int c = q & 1, isQ = q >> 1;
        float acc = isQ ? bc[c] : 0.f;
        int hoff = isQ * HID;
        #pragma unroll
        for (int hh = 0; hh < HID; ++hh)
            acc += A_s[r * HID + hh] * Wc[(hoff + hh) * 2 + c];
        int i = i0 + r;
        if (isQ) Qbuf[i * 2 + c] = acc;
        else     Pbuf[i * 2 + c] = acc;
    }
}

// ---------- stage 2: out[i,j,c] = relu(P[i,c] + Qb[j,c]), f32 output ----------
// grid (8, 256) x 256 threads. Thread: 2 j's (one float4 = 16B, lane-consecutive
// -> each store instruction covers 1 KB fully contiguous) x 16 i rows.
// Plain stores (no nt): match the 6.4 TB/s fill-kernel store path.
__global__ __launch_bounds__(256) void stage2(
    const float* __restrict__ Pbuf, const float* __restrict__ Qbuf,
    float* __restrict__ out)
{
    const int tid = threadIdx.x;
    const int j0  = blockIdx.x * 512 + tid * 2;   // 2 j's per thread
    const int i0  = blockIdx.y * 16;

    float4n q = *(const float4n*)(Qbuf + (size_t)j0 * 2);  // Qb[j0],Qb[j0+1]

    #pragma unroll
    for (int r = 0; r < 16; ++r) {
        int i = i0 + r;
        float p0 = Pbuf[i * 2], p1 = Pbuf[i * 2 + 1];  // block-uniform -> scalar
        float4n o;
        o.x = fmaxf(p0 + q.x, 0.f);
        o.y = fmaxf(p1 + q.y, 0.f);
        o.z = fmaxf(p0 + q.z, 0.f);
        o.w = fmaxf(p1 + q.w, 0.f);
        *(float4n*)(out + ((size_t)i * NUMW + j0) * 2) = o;
    }
}

extern "C" void kernel_launch(void* const* d_in, const int* in_sizes, int n_in,
                              void* d_out, int out_size, void* d_ws, size_t ws_size,
                              hipStream_t stream) {
    const float* oo = (const float*)d_in[0];
    const float* Wp = (const float*)d_in[1];
    const float* bp = (const float*)d_in[2];
    const float* Wc = (const float*)d_in[3];
    const float* bc = (const float*)d_in[4];

    float* Pbuf = (float*)d_ws;              // 4096*2 f32
    float* Qbuf = Pbuf + NUMW * 2;           // 4096*2 f32 (bc folded in)

    stage1<<<dim3(NUMW / 8), 256, 0, stream>>>(oo, Wp, bp, Wc, bc, Pbuf, Qbuf);
    stage2<<<dim3(8, 256), 256, 0, stream>>>(Pbuf, Qbuf, (float*)d_out);
}